// Round 4
// baseline (3418.335 us; speedup 1.0000x reference)
//
#include <hip/hip_runtime.h>
#include <cstdint>

typedef unsigned short u16;
typedef __attribute__((ext_vector_type(8))) short short8;   // 8 bf16 = 4 VGPRs (MFMA A/B frag)
typedef __attribute__((ext_vector_type(4))) float floatx4;  // MFMA C/D frag

typedef __attribute__((address_space(1))) void as1_void;
typedef __attribute__((address_space(3))) void as3_void;

__device__ __forceinline__ float b2f(u16 u) {
  return __uint_as_float(((unsigned int)u) << 16);
}
__device__ __forceinline__ u16 f2b(float f) {
  unsigned int x = __float_as_uint(f);
  x += 0x7fffu + ((x >> 16) & 1u);   // round-to-nearest-even
  return (u16)(x >> 16);
}
// dtype-adaptive element load from a raw input (f32flag ? float : bf16)
__device__ __forceinline__ float ldf(const void* p, size_t i, int f32) {
  return f32 ? ((const float*)p)[i] : b2f(((const u16*)p)[i]);
}

// async global->LDS, 16B per lane; LDS dest = wave-uniform base + lane*16.
// Proper compiler addrspacecasts (no uintptr round-trip).
__device__ __forceinline__ void gl_lds16(const u16* g, u16* l) {
  __builtin_amdgcn_global_load_lds((const as1_void*)g, (as3_void*)l, 16, 0, 0);
}

// ---------------------------------------------------------------------------
// GEMM: C[M,N] = A[M,K] @ B[K,N], BT is N x K row-major, all bf16 canonical.
// 128x128 tile, BK=64, 4 waves; XOR-swizzled LDS chunks; 16x16x32 bf16 MFMA.
// EPI: 0 f32 acc+bias; 1 bf16 gelu(acc+bias); 2 conv epilogue; 3 bf16 acc+bias.
// GATHER: A row m, k -> emb[tok[m*16 + k/512]][k%512]
// ---------------------------------------------------------------------------
template<int EPI, bool GATHER>
__global__ __launch_bounds__(256)
void gemm_bt(const u16* __restrict__ A, const u16* __restrict__ BT,
             int M, int K, int N,
             const u16* __restrict__ bias,
             float* __restrict__ outf, u16* __restrict__ outb,
             const int* __restrict__ tok, const u16* __restrict__ emb,
             const u16* __restrict__ pos, float* __restrict__ xf, u16* __restrict__ xb)
{
  __shared__ u16 lds[16384];
  u16* Al = lds;
  u16* Bl = lds + 8192;
  const int tid  = threadIdx.x;
  const int wave = tid >> 6, lane = tid & 63;
  const int m0 = blockIdx.x * 128, n0 = blockIdx.y * 128;
  const int wy = wave & 1, wx = wave >> 1;

  floatx4 acc[4][4];
#pragma unroll
  for (int i = 0; i < 4; ++i)
#pragma unroll
    for (int j = 0; j < 4; ++j) acc[i][j] = (floatx4){0.f, 0.f, 0.f, 0.f};

  for (int k0 = 0; k0 < K; k0 += 64) {
#pragma unroll
    for (int t = 0; t < 4; ++t) {
      int slot = t * 256 + wave * 64 + lane;
      int r = slot >> 3, cp = slot & 7;
      int c = cp ^ (r & 7);                 // swizzle on source chunk
      int grow = m0 + r; if (grow >= M) grow = M - 1;
      const u16* g;
      if (GATHER) {
        int k = k0 + c * 8;
        g = emb + ((size_t)tok[grow * 16 + (k >> 9)] * 512 + (k & 511));
      } else {
        g = A + ((size_t)grow * K + k0 + c * 8);
      }
      gl_lds16(g, Al + (size_t)(t * 256 + wave * 64) * 8);
    }
#pragma unroll
    for (int t = 0; t < 4; ++t) {
      int slot = t * 256 + wave * 64 + lane;
      int r = slot >> 3, cp = slot & 7;
      int c = cp ^ (r & 7);
      const u16* g = BT + ((size_t)(n0 + r) * K + k0 + c * 8);
      gl_lds16(g, Bl + (size_t)(t * 256 + wave * 64) * 8);
    }
    __syncthreads();

#pragma unroll
    for (int ks = 0; ks < 2; ++ks) {
      short8 af[4], bfr[4];
#pragma unroll
      for (int mt = 0; mt < 4; ++mt) {
        int r = wy * 64 + mt * 16 + (lane & 15);
        int ch = ks * 4 + (lane >> 4);
        af[mt] = *(const short8*)(Al + (size_t)(r * 8 + (ch ^ (r & 7))) * 8);
      }
#pragma unroll
      for (int nt = 0; nt < 4; ++nt) {
        int r = wx * 64 + nt * 16 + (lane & 15);
        int ch = ks * 4 + (lane >> 4);
        bfr[nt] = *(const short8*)(Bl + (size_t)(r * 8 + (ch ^ (r & 7))) * 8);
      }
#pragma unroll
      for (int mt = 0; mt < 4; ++mt)
#pragma unroll
        for (int nt = 0; nt < 4; ++nt)
          acc[mt][nt] = __builtin_amdgcn_mfma_f32_16x16x32_bf16(af[mt], bfr[nt], acc[mt][nt], 0, 0, 0);
    }
    __syncthreads();
  }

  // epilogue: C/D layout col = lane&15, row = (lane>>4)*4 + reg
  const int rb = m0 + wy * 64 + ((lane >> 4) << 2);
  const int cb = n0 + wx * 64 + (lane & 15);
#pragma unroll
  for (int mt = 0; mt < 4; ++mt) {
#pragma unroll
    for (int rr = 0; rr < 4; ++rr) {
      int row = rb + mt * 16 + rr;
      if (row >= M) continue;
#pragma unroll
      for (int nt = 0; nt < 4; ++nt) {
        int col = cb + nt * 16;
        float v = acc[mt][nt][rr] + b2f(bias[col]);
        if (EPI == 0) {
          outf[(size_t)row * N + col] = v;
        } else if (EPI == 1) {
          float gl = 0.5f * v * (1.0f + erff(v * 0.70710678118654752f));
          outb[(size_t)row * N + col] = f2b(gl);
        } else if (EPI == 3) {
          outb[(size_t)row * N + col] = f2b(v);
        } else {  // conv: row = b*256 + n -> x[b, 1+n]
          int bb = row >> 8, ss = (row & 255) + 1;
          v += b2f(pos[ss * 512 + col]);
          size_t o = ((size_t)(bb * 257 + ss)) * 512 + col;
          xf[o] = v;
          xb[o] = f2b(v);
        }
      }
    }
  }
}

// dtype detect: input_mask is all 1.0. f32 -> u16[0]==0x0000, bf16 -> 0x3F80.
__global__ void detect_kernel(const void* mask, int* flag)
{
  if (threadIdx.x == 0 && blockIdx.x == 0)
    flag[0] = (((const u16*)mask)[0] == 0) ? 1 : 0;
}

// raw float input (f32 or bf16 per flag) -> canonical bf16, with element offset
__global__ __launch_bounds__(256)
void cvt_kernel(const void* __restrict__ src, u16* __restrict__ dst, int n,
                const int* __restrict__ flag)
{
  int f = flag[0];
  int i = blockIdx.x * 256 + threadIdx.x;
  if (i < n) dst[i] = f2b(ldf(src, i, f));
}

// raw (R,C) matrix at element offset eoff -> canonical bf16 (C,R)
__global__ __launch_bounds__(256)
void transpose_any(const void* __restrict__ in, size_t eoff,
                   u16* __restrict__ out, int R, int C,
                   const int* __restrict__ flag)
{
  __shared__ u16 tile[32][33];
  int f = flag[0];
  int c0 = blockIdx.x * 32, r0 = blockIdx.y * 32;
  int tx = threadIdx.x, ty = threadIdx.y;
#pragma unroll
  for (int i = 0; i < 32; i += 8)
    tile[ty + i][tx] = f2b(ldf(in, eoff + (size_t)(r0 + ty + i) * C + (c0 + tx), f));
  __syncthreads();
#pragma unroll
  for (int i = 0; i < 32; i += 8)
    out[(size_t)(c0 + ty + i) * R + (r0 + tx)] = tile[tx][ty + i];
}

// convT[o][p*512+i] = conv_w[o][i][p]   (one block per o), raw -> bf16
__global__ __launch_bounds__(256)
void conv_repack(const void* __restrict__ w, u16* __restrict__ wt,
                 const int* __restrict__ flag)
{
  __shared__ u16 t[8192];
  int f = flag[0];
  int o = blockIdx.x, tid = threadIdx.x;
  for (int i = tid; i < 8192; i += 256)
    t[i] = f2b(ldf(w, (size_t)o * 8192 + i, f));
  __syncthreads();
  u16* dst = wt + (size_t)o * 8192;
  for (int j = tid; j < 8192; j += 256) {
    int p = j >> 9, i = j & 511;
    dst[j] = t[i * 16 + p];
  }
}

// x[b,0,:] = cls + pos[0]   (canonical bf16 inputs)
__global__ __launch_bounds__(256)
void cls_kernel(const u16* __restrict__ cls, const u16* __restrict__ pos,
                float* __restrict__ xf, u16* __restrict__ xb)
{
  int b = blockIdx.x, tid = threadIdx.x;
  for (int i = tid; i < 512; i += 256) {
    float v = b2f(cls[i]) + b2f(pos[i]);
    size_t o = ((size_t)b * 257) * 512 + i;
    xf[o] = v;
    xb[o] = f2b(v);
  }
}

__global__ __launch_bounds__(256)
void lengths_kernel(const void* __restrict__ mask, float* __restrict__ lens,
                    const int* __restrict__ flag)
{
  __shared__ float red[4];
  int f = flag[0];
  int b = blockIdx.x, tid = threadIdx.x;
  float s = 0.f;
  for (int i = tid; i < 4096; i += 256) s += ldf(mask, (size_t)b * 4096 + i, f);
#pragma unroll
  for (int o = 1; o < 64; o <<= 1) s += __shfl_xor(s, o);
  if ((tid & 63) == 0) red[tid >> 6] = s;
  __syncthreads();
  if (tid == 0) lens[b] = ceilf((red[0] + red[1] + red[2] + red[3] + 1.0f) * (1.0f / 16.0f));
}

// RoPE + elu+1 on q and k (in place); k additionally masked by (s < len[b]).
__global__ __launch_bounds__(256)
void rope_elu(float* __restrict__ q, float* __restrict__ k, const float* __restrict__ lens)
{
  int i = blockIdx.x * 256 + threadIdx.x;   // exactly 8224*256 threads
  int j = i & 31, h = (i >> 5) & 7, t = i >> 8;   // t = b*257+s
  int s = t % 257, b = t / 257;
  size_t base = (size_t)t * 512 + h * 64 + j;
  float inv = __expf(-(float)j * (9.210340371976184f / 32.0f));  // 10000^(-j/32)
  float ang = (float)s * inv;
  float c, sn;
  __sincosf(ang, &sn, &c);
  float q1 = q[base], q2 = q[base + 32];
  float r1 = q1 * c - q2 * sn, r2 = q2 * c + q1 * sn;
  q[base]      = (r1 > 0.f) ? (r1 + 1.f) : __expf(r1);
  q[base + 32] = (r2 > 0.f) ? (r2 + 1.f) : __expf(r2);
  float msk = ((float)s < lens[b]) ? 1.f : 0.f;
  float k1 = k[base], k2 = k[base + 32];
  r1 = k1 * c - k2 * sn; r2 = k2 * c + k1 * sn;
  k[base]      = ((r1 > 0.f) ? (r1 + 1.f) : __expf(r1)) * msk;
  k[base + 32] = ((r2 > 0.f) ? (r2 + 1.f) : __expf(r2)) * msk;
}

// kv[b,h,d,m] = sum_s kf[b,s,h,d]*v[b,s,h,m] ; ksum[b,h,d] = sum_s kf
__global__ __launch_bounds__(256)
void kv_kernel(const float* __restrict__ kf, const u16* __restrict__ v,
               float* __restrict__ kv, float* __restrict__ ksum)
{
  int bh = blockIdx.x, b = bh >> 3, h = bh & 7;
  int tid = threadIdx.x, d = tid & 63, mg = tid >> 6;
  float acc[16];
#pragma unroll
  for (int j = 0; j < 16; ++j) acc[j] = 0.f;
  float ks = 0.f;
  for (int s = 0; s < 257; ++s) {
    size_t base = ((size_t)(b * 257 + s)) * 512 + h * 64;
    float kfv = kf[base + d];
    const u16* vr = v + base + mg * 16;
#pragma unroll
    for (int j = 0; j < 16; ++j) acc[j] += kfv * b2f(vr[j]);
    ks += kfv;
  }
  float* kvo = kv + (size_t)bh * 4096 + d * 64 + mg * 16;
#pragma unroll
  for (int j = 0; j < 16; ++j) kvo[j] = acc[j];
  if (mg == 0) ksum[(size_t)bh * 64 + d] = ks;
}

// z[b,s,h] = 1/(qf . ksum + 1e-6)
__global__ __launch_bounds__(256)
void z_kernel(const float* __restrict__ qf, const float* __restrict__ ksum,
              float* __restrict__ z)
{
  int i = blockIdx.x * 256 + threadIdx.x;
  if (i >= 65792) return;
  int h = i & 7, t = i >> 3, b = t / 257;
  const float* qr = qf + (size_t)t * 512 + h * 64;
  const float* kr = ksum + ((size_t)b * 8 + h) * 64;
  float s = 0.f;
#pragma unroll
  for (int d = 0; d < 64; ++d) s += qr[d] * kr[d];
  z[i] = 1.0f / (s + 1e-6f);
}

// attn[b,s,h*64+m] = z * sum_d qf[d]*kv[d,m] -> bf16
__global__ __launch_bounds__(256)
void attn_kernel(const float* __restrict__ qf, const float* __restrict__ kv,
                 const float* __restrict__ z, u16* __restrict__ attn)
{
  __shared__ float kvs[4096];
  int bh = blockIdx.x, b = bh >> 3, h = bh & 7;
  int tid = threadIdx.x;
  const float* kvg = kv + (size_t)bh * 4096;
  for (int i = tid; i < 4096; i += 256) kvs[i] = kvg[i];
  __syncthreads();
  int m = tid & 63;
  for (int s = tid >> 6; s < 257; s += 4) {
    size_t base = ((size_t)(b * 257 + s)) * 512 + h * 64;
    float zz = z[(b * 257 + s) * 8 + h];
    float sum = 0.f;
#pragma unroll
    for (int d = 0; d < 64; ++d) sum += qf[base + d] * kvs[d * 64 + m];
    attn[base + m] = f2b(sum * zz);
  }
}

// LayerNorm over D=512 of (xin+add); canonical bf16 s/b; writes f32 + bf16.
__global__ __launch_bounds__(256)
void ln_kernel(const float* __restrict__ xin, const float* __restrict__ add,
               const u16* __restrict__ s, const u16* __restrict__ b,
               float* __restrict__ xoutf, u16* __restrict__ xoutb)
{
  __shared__ float red[8];
  int row = blockIdx.x, tid = threadIdx.x;
  size_t base = (size_t)row * 512;
  float v0 = xin[base + tid] + add[base + tid];
  float v1 = xin[base + tid + 256] + add[base + tid + 256];
  float sum = v0 + v1, sq = v0 * v0 + v1 * v1;
#pragma unroll
  for (int o = 1; o < 64; o <<= 1) { sum += __shfl_xor(sum, o); sq += __shfl_xor(sq, o); }
  if ((tid & 63) == 0) { red[tid >> 6] = sum; red[4 + (tid >> 6)] = sq; }
  __syncthreads();
  sum = red[0] + red[1] + red[2] + red[3];
  sq  = red[4] + red[5] + red[6] + red[7];
  float mean = sum * (1.f / 512.f);
  float var  = sq * (1.f / 512.f) - mean * mean;
  float rs = rsqrtf(fmaxf(var, 0.f) + 1e-5f);
  float o0 = (v0 - mean) * rs * b2f(s[tid]) + b2f(b[tid]);
  float o1 = (v1 - mean) * rs * b2f(s[tid + 256]) + b2f(b[tid + 256]);
  xoutf[base + tid] = o0;       xoutf[base + tid + 256] = o1;
  xoutb[base + tid] = f2b(o0);  xoutb[base + tid + 256] = f2b(o1);
}

// final LN on x[b,0,:] + projection to 4 classes; output dtype per flag
__global__ __launch_bounds__(256)
void head_kernel(const float* __restrict__ x, const u16* __restrict__ ls,
                 const u16* __restrict__ lb, const u16* __restrict__ ow,
                 const u16* __restrict__ ob, void* __restrict__ outv,
                 const int* __restrict__ flag)
{
  __shared__ float red[8];
  __shared__ float pr[4][4];
  int b = blockIdx.x, tid = threadIdx.x;
  const float* xr = x + (size_t)b * 257 * 512;
  float v0 = xr[tid], v1 = xr[tid + 256];
  float sum = v0 + v1, sq = v0 * v0 + v1 * v1;
#pragma unroll
  for (int o = 1; o < 64; o <<= 1) { sum += __shfl_xor(sum, o); sq += __shfl_xor(sq, o); }
  if ((tid & 63) == 0) { red[tid >> 6] = sum; red[4 + (tid >> 6)] = sq; }
  __syncthreads();
  sum = red[0] + red[1] + red[2] + red[3];
  sq  = red[4] + red[5] + red[6] + red[7];
  float mean = sum * (1.f / 512.f);
  float var = sq * (1.f / 512.f) - mean * mean;
  float rs = rsqrtf(fmaxf(var, 0.f) + 1e-5f);
  float o0 = (v0 - mean) * rs * b2f(ls[tid]) + b2f(lb[tid]);
  float o1 = (v1 - mean) * rs * b2f(ls[tid + 256]) + b2f(lb[tid + 256]);
  float p[4];
#pragma unroll
  for (int c = 0; c < 4; ++c)
    p[c] = o0 * b2f(ow[tid * 4 + c]) + o1 * b2f(ow[(tid + 256) * 4 + c]);
#pragma unroll
  for (int c = 0; c < 4; ++c)
#pragma unroll
    for (int o = 1; o < 64; o <<= 1) p[c] += __shfl_xor(p[c], o);
  if ((tid & 63) == 0)
#pragma unroll
    for (int c = 0; c < 4; ++c) pr[tid >> 6][c] = p[c];
  __syncthreads();
  if (tid < 4) {
    float s = pr[0][tid] + pr[1][tid] + pr[2][tid] + pr[3][tid] + b2f(ob[tid]);
    if (flag[0]) ((float*)outv)[b * 4 + tid] = s;
    else         ((u16*)outv)[b * 4 + tid] = f2b(s);
  }
}

// diagnostic: report ws_size (in MiB) through the output when ws is too small
__global__ __launch_bounds__(256)
void diag_kernel(u16* out, int n, float v)
{
  int i = blockIdx.x * 256 + threadIdx.x;
  if (i < n) out[i] = f2b(v);
}

// ---------------------------------------------------------------------------
extern "C" void kernel_launch(void* const* d_in, const int* in_sizes, int n_in,
                              void* d_out, int out_size, void* d_ws, size_t ws_size,
                              hipStream_t stream)
{
  const int*  inputs = (const int*)d_in[0];
  const void* imask  = d_in[1];
  const void* emb    = d_in[2];
  const void* conv_w = d_in[3];
  const void* conv_b = d_in[4];
  const void* pos    = d_in[5];
  const void* cls    = d_in[6];
  const void* Wq = d_in[7];  const void* bq = d_in[8];
  const void* Wk = d_in[9];  const void* bk = d_in[10];
  const void* Wv = d_in[11]; const void* bv = d_in[12];
  const void* Wo = d_in[13]; const void* bo = d_in[14];
  const void* ln1s = d_in[15]; const void* ln1b = d_in[16];
  const void* ln2s = d_in[17]; const void* ln2b = d_in[18];
  const void* W1 = d_in[19]; const void* b1 = d_in[20];
  const void* W2 = d_in[21]; const void* b2 = d_in[22];
  const void* lnfs = d_in[23]; const void* lnfb = d_in[24];
  const void* outw = d_in[25]; const void* outbb = d_in[26];

  // ---- workspace carve, lifetime-aliased; ~83.3 MiB ----
  const size_t NEED = 87500000;
  if (ws_size < NEED) {
    diag_kernel<<<(out_size + 255) / 256, 256, 0, stream>>>(
        (u16*)d_out, out_size, (float)((double)ws_size / 1048576.0));
    return;
  }
  char* p = (char*)d_ws;
  auto take = [&](size_t n) { char* r = p; p += (n + 255) & ~(size_t)255; return r; };
  u16*   WqT = (u16*)take(524288);        // per-layer 512x512 transposed (bf16)
  u16*   WkT = (u16*)take(524288);
  u16*   WvT = (u16*)take(524288);
  u16*   WoT = (u16*)take(524288);
  u16*   W1T = (u16*)take(2097152);       // per-layer (2048,512)
  u16*   W2T = (u16*)take(2097152);       // per-layer (512,2048)
  float* xf  = (float*)take(16842752);    // residual f32, persists
  u16*   xb  = (u16*)take(8421376);       // residual bf16 shadow, persists
  // arena: pre-loop = canonical emb bf16 (32.77MB); in-loop = qb|kb (attnb over
  // dead kb); FF phase = y1 (exact fit 33,685,504 B).
  char*  arena = take(16842752ull * 2);
  float* qb    = (float*)arena;
  float* kb    = (float*)(arena + 16842752);
  u16*   embC  = (u16*)arena;
  u16*   attnb = (u16*)(arena + 16842752);
  u16*   y1    = (u16*)arena;
  // C block: pre-loop = convT (8.39MB); in-loop = vb bf16 then t0 f32.
  char*  Cblk  = take(16842752);
  u16*   convT = (u16*)Cblk;
  u16*   vb    = (u16*)Cblk;
  float* t0    = (float*)Cblk;
  float* kvb   = (float*)take(4194304);
  float* ksumb = (float*)take(65536);
  float* zb    = (float*)take(263168);
  float* lens  = (float*)take(256);
  int*   flag  = (int*)take(256);
  u16* conv_bC = (u16*)take(1024);
  u16* posC    = (u16*)take(524288);
  u16* clsC    = (u16*)take(1024);
  u16* bqC     = (u16*)take(8192);
  u16* bkC     = (u16*)take(8192);
  u16* bvC     = (u16*)take(8192);
  u16* boC     = (u16*)take(8192);
  u16* ln1sC   = (u16*)take(8192);
  u16* ln1bC   = (u16*)take(8192);
  u16* ln2sC   = (u16*)take(8192);
  u16* ln2bC   = (u16*)take(8192);
  u16* b1C     = (u16*)take(32768);
  u16* b2C     = (u16*)take(8192);
  u16* lnfsC   = (u16*)take(1024);
  u16* lnfbC   = (u16*)take(1024);
  u16* outwC   = (u16*)take(4096);
  u16* outbC   = (u16*)take(256);

  detect_kernel<<<1, 64, 0, stream>>>(imask, flag);

  // canonicalize raw float inputs -> bf16
  cvt_kernel<<<64000, 256, 0, stream>>>(emb, embC, 16384000, flag);
  conv_repack<<<512, 256, 0, stream>>>(conv_w, convT, flag);
  cvt_kernel<<<2, 256, 0, stream>>>(conv_b, conv_bC, 512, flag);
  cvt_kernel<<<1024, 256, 0, stream>>>(pos, posC, 262144, flag);
  cvt_kernel<<<2, 256, 0, stream>>>(cls, clsC, 512, flag);
  cvt_kernel<<<16, 256, 0, stream>>>(bq, bqC, 4096, flag);
  cvt_kernel<<<16, 256, 0, stream>>>(bk, bkC, 4096, flag);
  cvt_kernel<<<16, 256, 0, stream>>>(bv, bvC, 4096, flag);
  cvt_kernel<<<16, 256, 0, stream>>>(bo, boC, 4096, flag);
  cvt_kernel<<<16, 256, 0, stream>>>(ln1s, ln1sC, 4096, flag);
  cvt_kernel<<<16, 256, 0, stream>>>(ln1b, ln1bC, 4096, flag);
  cvt_kernel<<<16, 256, 0, stream>>>(ln2s, ln2sC, 4096, flag);
  cvt_kernel<<<16, 256, 0, stream>>>(ln2b, ln2bC, 4096, flag);
  cvt_kernel<<<64, 256, 0, stream>>>(b1, b1C, 16384, flag);
  cvt_kernel<<<16, 256, 0, stream>>>(b2, b2C, 4096, flag);
  cvt_kernel<<<2, 256, 0, stream>>>(lnfs, lnfsC, 512, flag);
  cvt_kernel<<<2, 256, 0, stream>>>(lnfb, lnfbC, 512, flag);
  cvt_kernel<<<8, 256, 0, stream>>>(outw, outwC, 2048, flag);
  cvt_kernel<<<1, 256, 0, stream>>>(outbb, outbC, 4, flag);
  lengths_kernel<<<32, 256, 0, stream>>>(imask, lens, flag);

  // patch conv: gathered-A GEMM (M=8192, K=8192, N=512) -> x[b,1+n]
  gemm_bt<2, true><<<dim3(64, 4), 256, 0, stream>>>(
      nullptr, convT, 8192, 8192, 512, conv_bC,
      nullptr, nullptr, inputs, embC, posC, xf, xb);
  cls_kernel<<<32, 256, 0, stream>>>(clsC, posC, xf, xb);

  for (int i = 0; i < 8; ++i) {
    const size_t o512 = (size_t)i * 262144;     // element offsets (dtype-free)
    const size_t o2k  = (size_t)i * 1048576;
    transpose_any<<<dim3(16, 16), dim3(32, 8), 0, stream>>>(Wq, o512, WqT, 512, 512, flag);
    transpose_any<<<dim3(16, 16), dim3(32, 8), 0, stream>>>(Wk, o512, WkT, 512, 512, flag);
    transpose_any<<<dim3(16, 16), dim3(32, 8), 0, stream>>>(Wv, o512, WvT, 512, 512, flag);
    transpose_any<<<dim3(16, 16), dim3(32, 8), 0, stream>>>(Wo, o512, WoT, 512, 512, flag);
    transpose_any<<<dim3(64, 16), dim3(32, 8), 0, stream>>>(W1, o2k, W1T, 512, 2048, flag);
    transpose_any<<<dim3(16, 64), dim3(32, 8), 0, stream>>>(W2, o2k, W2T, 2048, 512, flag);

    gemm_bt<0, false><<<dim3(65, 4), 256, 0, stream>>>(
        xb, WqT, 8224, 512, 512, bqC + i * 512,
        qb, nullptr, nullptr, nullptr, nullptr, nullptr, nullptr);
    gemm_bt<0, false><<<dim3(65, 4), 256, 0, stream>>>(
        xb, WkT, 8224, 512, 512, bkC + i * 512,
        kb, nullptr, nullptr, nullptr, nullptr, nullptr, nullptr);
    gemm_bt<3, false><<<dim3(65, 4), 256, 0, stream>>>(
        xb, WvT, 8224, 512, 512, bvC + i * 512,
        nullptr, vb, nullptr, nullptr, nullptr, nullptr, nullptr);
    rope_elu<<<8224, 256, 0, stream>>>(qb, kb, lens);
    kv_kernel<<<256, 256, 0, stream>>>(kb, vb, kvb, ksumb);      // last read kb, vb
    z_kernel<<<257, 256, 0, stream>>>(qb, ksumb, zb);
    attn_kernel<<<256, 256, 0, stream>>>(qb, kvb, zb, attnb);    // last read qb
    gemm_bt<0, false><<<dim3(65, 4), 256, 0, stream>>>(
        attnb, WoT, 8224, 512, 512, boC + i * 512,
        t0, nullptr, nullptr, nullptr, nullptr, nullptr, nullptr);
    ln_kernel<<<8224, 256, 0, stream>>>(xf, t0, ln1sC + i * 512, ln1bC + i * 512, xf, xb);
    gemm_bt<1, false><<<dim3(65, 16), 256, 0, stream>>>(
        xb, W1T, 8224, 512, 2048, b1C + i * 2048,
        nullptr, y1, nullptr, nullptr, nullptr, nullptr, nullptr);
    gemm_bt<0, false><<<dim3(65, 4), 256, 0, stream>>>(
        y1, W2T, 8224, 2048, 512, b2C + i * 512,
        t0, nullptr, nullptr, nullptr, nullptr, nullptr, nullptr);
    ln_kernel<<<8224, 256, 0, stream>>>(xf, t0, ln2sC + i * 512, ln2bC + i * 512, xf, xb);
  }

  head_kernel<<<32, 256, 0, stream>>>(xf, lnfsC, lnfbC, outwC, outbC, d_out, flag);
}

// Round 5
// 2827.740 us; speedup vs baseline: 1.2089x; 1.2089x over previous
//
#include <hip/hip_runtime.h>
#include <cstdint>

typedef unsigned short u16;
typedef __attribute__((ext_vector_type(8))) short short8;   // 8 bf16 (MFMA A/B frag)
typedef __attribute__((ext_vector_type(4))) float floatx4;  // MFMA C/D frag

typedef __attribute__((address_space(1))) void as1_void;
typedef __attribute__((address_space(3))) void as3_void;

__device__ __forceinline__ float b2f(u16 u) {
  return __uint_as_float(((unsigned int)u) << 16);
}
__device__ __forceinline__ u16 f2b(float f) {
  unsigned int x = __float_as_uint(f);
  x += 0x7fffu + ((x >> 16) & 1u);   // round-to-nearest-even
  return (u16)(x >> 16);
}
// dtype-adaptive element load from a raw input (f32flag ? float : bf16)
__device__ __forceinline__ float ldf(const void* p, size_t i, int f32) {
  return f32 ? ((const float*)p)[i] : b2f(((const u16*)p)[i]);
}
__device__ __forceinline__ void gl_lds16(const u16* g, u16* l) {
  __builtin_amdgcn_global_load_lds((const as1_void*)g, (as3_void*)l, 16, 0, 0);
}

// ---------------------------------------------------------------------------
// GEMM: C[M,N] = A[M,K] @ B[K,N], BT is N x K row-major bf16.
// Tile TM x 128, BK=64, 4 waves (wave tile (TM/2) x 64). XOR-swizzled LDS.
// EPI: 0 f32 acc+bias -> outf
//      1 bf16 gelu(acc+bias) -> outb
//      2 conv epilogue: acc+bias+pos[s] -> xf/xb at (b, s=1+n)
//      4 fused QKV epilogue (N=1536): region q/k -> rope+elu(+mask) f32 to
//        outf/outf2; region v -> bf16 outb. bias is the stacked qkv bias.
// GATHER: A row m, k -> emb[tok[m*16 + k/512]][k%512]
// ---------------------------------------------------------------------------
template<int TM, int EPI, bool GATHER>
__global__ __launch_bounds__(256)
void gemm_bt(const u16* __restrict__ A, const u16* __restrict__ BT,
             int M, int K, int N,
             const u16* __restrict__ bias,
             float* __restrict__ outf, float* __restrict__ outf2,
             u16* __restrict__ outb,
             const int* __restrict__ tok, const u16* __restrict__ emb,
             const u16* __restrict__ pos, float* __restrict__ xf, u16* __restrict__ xb,
             const float* __restrict__ lens)
{
  constexpr int MT = TM / 32;            // m-tiles per wave
  constexpr int AISS = (TM * 8) / 256;   // A staging issues
  __shared__ u16 lds[TM * 64 + 8192];
  u16* Al = lds;
  u16* Bl = lds + TM * 64;
  const int tid  = threadIdx.x;
  const int wave = tid >> 6, lane = tid & 63;
  const int m0 = blockIdx.x * TM, n0 = blockIdx.y * 128;
  const int wy = wave & 1, wx = wave >> 1;

  floatx4 acc[MT][4];
#pragma unroll
  for (int i = 0; i < MT; ++i)
#pragma unroll
    for (int j = 0; j < 4; ++j) acc[i][j] = (floatx4){0.f, 0.f, 0.f, 0.f};

  for (int k0 = 0; k0 < K; k0 += 64) {
#pragma unroll
    for (int t = 0; t < AISS; ++t) {        // A tile: TM rows x 64 k
      int slot = t * 256 + wave * 64 + lane;
      int r = slot >> 3, cp = slot & 7;
      int c = cp ^ (r & 7);                 // swizzle on source chunk
      int grow = m0 + r; if (grow >= M) grow = M - 1;
      const u16* g;
      if (GATHER) {
        int k = k0 + c * 8;
        g = emb + ((size_t)tok[grow * 16 + (k >> 9)] * 512 + (k & 511));
      } else {
        g = A + ((size_t)grow * K + k0 + c * 8);
      }
      gl_lds16(g, Al + (size_t)(t * 256 + wave * 64) * 8);
    }
#pragma unroll
    for (int t = 0; t < 4; ++t) {           // B tile: 128 n-rows x 64 k
      int slot = t * 256 + wave * 64 + lane;
      int r = slot >> 3, cp = slot & 7;
      int c = cp ^ (r & 7);
      const u16* g = BT + ((size_t)(n0 + r) * K + k0 + c * 8);
      gl_lds16(g, Bl + (size_t)(t * 256 + wave * 64) * 8);
    }
    __syncthreads();

#pragma unroll
    for (int ks = 0; ks < 2; ++ks) {
      short8 af[MT], bfr[4];
#pragma unroll
      for (int mt = 0; mt < MT; ++mt) {
        int r = wy * (TM / 2) + mt * 16 + (lane & 15);
        int ch = ks * 4 + (lane >> 4);
        af[mt] = *(const short8*)(Al + (size_t)(r * 8 + (ch ^ (r & 7))) * 8);
      }
#pragma unroll
      for (int nt = 0; nt < 4; ++nt) {
        int r = wx * 64 + nt * 16 + (lane & 15);
        int ch = ks * 4 + (lane >> 4);
        bfr[nt] = *(const short8*)(Bl + (size_t)(r * 8 + (ch ^ (r & 7))) * 8);
      }
#pragma unroll
      for (int mt = 0; mt < MT; ++mt)
#pragma unroll
        for (int nt = 0; nt < 4; ++nt)
          acc[mt][nt] = __builtin_amdgcn_mfma_f32_16x16x32_bf16(af[mt], bfr[nt], acc[mt][nt], 0, 0, 0);
    }
    __syncthreads();
  }

  // epilogue: C/D layout col = lane&15 (+nt*16), row = (lane>>4)*4 + reg
  const int rb = m0 + wy * (TM / 2) + ((lane >> 4) << 2);
  const int cb = n0 + wx * 64 + (lane & 15);
#pragma unroll
  for (int mt = 0; mt < MT; ++mt) {
#pragma unroll
    for (int rr = 0; rr < 4; ++rr) {
      int row = rb + mt * 16 + rr;
      if (row >= M) continue;
      if (EPI == 4) {
        int region = n0 >> 9;              // 0=q 1=k 2=v
        int b = row / 257, s = row - b * 257;
        if (region == 2) {
#pragma unroll
          for (int nt = 0; nt < 4; ++nt) {
            int col = cb + nt * 16;
            float v = acc[mt][nt][rr] + b2f(bias[col]);
            outb[(size_t)row * 512 + (col - 1024)] = f2b(v);
          }
        } else {
          float msk = (region == 1) ? (((float)s < lens[b]) ? 1.f : 0.f) : 1.f;
#pragma unroll
          for (int nt = 0; nt < 2; ++nt) {
            int ngL = cb + nt * 16, ngH = ngL + 32;
            int jl = nt * 16 + (lane & 15);           // rotation index in [0,32)
            float x1 = acc[mt][nt][rr]     + b2f(bias[ngL]);
            float x2 = acc[mt][nt + 2][rr] + b2f(bias[ngH]);
            float ang = (float)s * __expf(-(float)jl * (9.210340371976184f / 32.0f));
            float sn, cs;
            __sincosf(ang, &sn, &cs);
            float rl = x1 * cs - x2 * sn;
            float rh = x2 * cs + x1 * sn;
            float eL = (rl > 0.f) ? (rl + 1.f) : __expf(rl);
            float eH = (rh > 0.f) ? (rh + 1.f) : __expf(rh);
            eL *= msk; eH *= msk;
            float* dst = (region == 0) ? outf : outf2;
            int colL = ngL - region * 512;
            dst[(size_t)row * 512 + colL]      = eL;
            dst[(size_t)row * 512 + colL + 32] = eH;
          }
        }
      } else {
#pragma unroll
        for (int nt = 0; nt < 4; ++nt) {
          int col = cb + nt * 16;
          float v = acc[mt][nt][rr] + b2f(bias[col]);
          if (EPI == 0) {
            outf[(size_t)row * N + col] = v;
          } else if (EPI == 1) {
            float gl = 0.5f * v * (1.0f + erff(v * 0.70710678118654752f));
            outb[(size_t)row * N + col] = f2b(gl);
          } else {  // EPI == 2, conv: row = b*256 + n -> x[b, 1+n]
            int bb = row >> 8, ss = (row & 255) + 1;
            v += b2f(pos[ss * 512 + col]);
            size_t o = ((size_t)(bb * 257 + ss)) * 512 + col;
            xf[o] = v;
            xb[o] = f2b(v);
          }
        }
      }
    }
  }
}

// dtype detect: input_mask is all 1.0. f32 -> u16[0]==0x0000, bf16 -> 0x3F80.
__global__ void detect_kernel(const void* mask, int* flag)
{
  if (threadIdx.x == 0 && blockIdx.x == 0)
    flag[0] = (((const u16*)mask)[0] == 0) ? 1 : 0;
}

// raw float input (f32 or bf16 per flag) -> canonical bf16
__global__ __launch_bounds__(256)
void cvt_kernel(const void* __restrict__ src, u16* __restrict__ dst, int n,
                const int* __restrict__ flag)
{
  int f = flag[0];
  int i = blockIdx.x * 256 + threadIdx.x;
  if (i < n) dst[i] = f2b(ldf(src, i, f));
}

// fused small-parameter canonicalization (one dispatch)
struct PCvt {
  const void *pos, *conv_b, *cls, *bq, *bk, *bv, *bo;
  const void *ln1s, *ln1b, *ln2s, *ln2b, *b1, *b2, *lnfs, *lnfb, *outw, *outb;
  u16 *posC, *conv_bC, *clsC, *bqkvC, *boC;
  u16 *ln1sC, *ln1bC, *ln2sC, *ln2bC, *b1C, *b2C, *lnfsC, *lnfbC, *outwC, *outbC;
  const int* flag;
};
__global__ __launch_bounds__(256)
void param_cvt(PCvt p)
{
  int f = p.flag[0];
  int seg = blockIdx.y;
  int i = blockIdx.x * 256 + threadIdx.x;
  switch (seg) {
    case 0:  if (i < 262144) p.posC[i]    = f2b(ldf(p.pos, i, f)); break;
    case 1:  if (i < 512)    p.conv_bC[i] = f2b(ldf(p.conv_b, i, f)); break;
    case 2:  if (i < 512)    p.clsC[i]    = f2b(ldf(p.cls, i, f)); break;
    case 3:  if (i < 12288) {                      // stacked qkv bias per layer
      int layer = i / 1536, r = i - layer * 1536;
      const void* s = (r < 512) ? p.bq : (r < 1024) ? p.bk : p.bv;
      int rr = r & 511;
      p.bqkvC[i] = f2b(ldf(s, (size_t)layer * 512 + rr, f));
    } break;
    case 4:  if (i < 4096)  p.boC[i]   = f2b(ldf(p.bo, i, f)); break;
    case 5:  if (i < 4096)  p.ln1sC[i] = f2b(ldf(p.ln1s, i, f)); break;
    case 6:  if (i < 4096)  p.ln1bC[i] = f2b(ldf(p.ln1b, i, f)); break;
    case 7:  if (i < 4096)  p.ln2sC[i] = f2b(ldf(p.ln2s, i, f)); break;
    case 8:  if (i < 4096)  p.ln2bC[i] = f2b(ldf(p.ln2b, i, f)); break;
    case 9:  if (i < 16384) p.b1C[i]   = f2b(ldf(p.b1, i, f)); break;
    case 10: if (i < 4096)  p.b2C[i]   = f2b(ldf(p.b2, i, f)); break;
    default:
      if (i < 512)        p.lnfsC[i]        = f2b(ldf(p.lnfs, i, f));
      else if (i < 1024)  p.lnfbC[i - 512]  = f2b(ldf(p.lnfb, (size_t)i - 512, f));
      else if (i < 3072)  p.outwC[i - 1024] = f2b(ldf(p.outw, (size_t)i - 1024, f));
      else if (i < 3076)  p.outbC[i - 3072] = f2b(ldf(p.outb, (size_t)i - 3072, f));
      break;
  }
}

// fused per-layer (or all-layer) weight transposes -> bf16 B^T buffers.
// grid.x = 3072 tiles: [0,768) Wq/Wk/Wv -> WqkvT, [768,1024) Wo, [1024,2048) W1,
// [2048,3072) W2. grid.y = layer - base. dst layer index = blockIdx.y.
struct XPose {
  const void *Wq, *Wk, *Wv, *Wo, *W1, *W2;
  u16 *WqkvT, *WoT, *W1T, *W2T;
  int base;
  const int* flag;
};
__global__ __launch_bounds__(256)
void xpose_layer(XPose xp)
{
  __shared__ u16 tile[32][33];
  int f = xp.flag[0];
  int layer = xp.base + blockIdx.y;
  int y = blockIdx.y;
  int t = blockIdx.x;
  const void* src; u16* dst; int R, C, cx, ry; size_t eoff;
  if (t < 1024) {                 // four 512x512 mats, 256 tiles each
    int wsel = t >> 8, tt = t & 255;
    R = 512; C = 512; cx = tt & 15; ry = tt >> 4;
    eoff = (size_t)layer * 262144;
    if (wsel < 3) { src = (wsel == 0) ? xp.Wq : (wsel == 1) ? xp.Wk : xp.Wv;
                    dst = xp.WqkvT + (size_t)y * 786432 + (size_t)wsel * 262144; }
    else          { src = xp.Wo; dst = xp.WoT + (size_t)y * 262144; }
  } else if (t < 2048) {          // W1 (512,2048): 64x16 tiles
    int tt = t - 1024;
    R = 512; C = 2048; cx = tt & 63; ry = tt >> 6;
    eoff = (size_t)layer * 1048576;
    src = xp.W1; dst = xp.W1T + (size_t)y * 1048576;
  } else {                        // W2 (2048,512): 16x64 tiles
    int tt = t - 2048;
    R = 2048; C = 512; cx = tt & 15; ry = tt >> 4;
    eoff = (size_t)layer * 1048576;
    src = xp.W2; dst = xp.W2T + (size_t)y * 1048576;
  }
  int c0 = cx * 32, r0 = ry * 32;
  int tx = threadIdx.x, ty = threadIdx.y;
#pragma unroll
  for (int i = 0; i < 32; i += 8)
    tile[ty + i][tx] = f2b(ldf(src, eoff + (size_t)(r0 + ty + i) * C + (c0 + tx), f));
  __syncthreads();
#pragma unroll
  for (int i = 0; i < 32; i += 8)
    dst[(size_t)(c0 + ty + i) * R + (r0 + tx)] = tile[tx][ty + i];
}

// convT[o][p*512+i] = conv_w[o][i][p]
__global__ __launch_bounds__(256)
void conv_repack(const void* __restrict__ w, u16* __restrict__ wt,
                 const int* __restrict__ flag)
{
  __shared__ u16 t[8192];
  int f = flag[0];
  int o = blockIdx.x, tid = threadIdx.x;
  for (int i = tid; i < 8192; i += 256)
    t[i] = f2b(ldf(w, (size_t)o * 8192 + i, f));
  __syncthreads();
  u16* dst = wt + (size_t)o * 8192;
  for (int j = tid; j < 8192; j += 256) {
    int p = j >> 9, i = j & 511;
    dst[j] = t[i * 16 + p];
  }
}

// x[b,0,:] = cls + pos[0]
__global__ __launch_bounds__(256)
void cls_kernel(const u16* __restrict__ cls, const u16* __restrict__ pos,
                float* __restrict__ xf, u16* __restrict__ xb)
{
  int b = blockIdx.x, tid = threadIdx.x;
  for (int i = tid; i < 512; i += 256) {
    float v = b2f(cls[i]) + b2f(pos[i]);
    size_t o = ((size_t)b * 257) * 512 + i;
    xf[o] = v;
    xb[o] = f2b(v);
  }
}

__global__ __launch_bounds__(256)
void lengths_kernel(const void* __restrict__ mask, float* __restrict__ lens,
                    const int* __restrict__ flag)
{
  __shared__ float red[4];
  int f = flag[0];
  int b = blockIdx.x, tid = threadIdx.x;
  float s = 0.f;
  for (int i = tid; i < 4096; i += 256) s += ldf(mask, (size_t)b * 4096 + i, f);
#pragma unroll
  for (int o = 1; o < 64; o <<= 1) s += __shfl_xor(s, o);
  if ((tid & 63) == 0) red[tid >> 6] = s;
  __syncthreads();
  if (tid == 0) lens[b] = ceilf((red[0] + red[1] + red[2] + red[3] + 1.0f) * (1.0f / 16.0f));
}

// kv[b,h,d,m] = sum_s kf[b,s,h,d]*v[b,s,h,m] ; ksum[b,h,d] = sum_s kf
__global__ __launch_bounds__(256)
void kv_kernel(const float* __restrict__ kf, const u16* __restrict__ v,
               float* __restrict__ kv, float* __restrict__ ksum)
{
  int bh = blockIdx.x, b = bh >> 3, h = bh & 7;
  int tid = threadIdx.x, d = tid & 63, mg = tid >> 6;
  float acc[16];
#pragma unroll
  for (int j = 0; j < 16; ++j) acc[j] = 0.f;
  float ks = 0.f;
  for (int s = 0; s < 257; ++s) {
    size_t base = ((size_t)(b * 257 + s)) * 512 + h * 64;
    float kfv = kf[base + d];
    const u16* vr = v + base + mg * 16;
#pragma unroll
    for (int j = 0; j < 16; ++j) acc[j] += kfv * b2f(vr[j]);
    ks += kfv;
  }
  float* kvo = kv + (size_t)bh * 4096 + d * 64 + mg * 16;
#pragma unroll
  for (int j = 0; j < 16; ++j) kvo[j] = acc[j];
  if (mg == 0) ksum[(size_t)bh * 64 + d] = ks;
}

// attn[b,s,h*64+m] = z * sum_d qf[d]*kv[d,m], z fused (wave-shuffle dot)
__global__ __launch_bounds__(256)
void attn_kernel(const float* __restrict__ qf, const float* __restrict__ kv,
                 const float* __restrict__ ksum, u16* __restrict__ attn)
{
  __shared__ float kvs[4096];
  __shared__ float kss[64];
  int bh = blockIdx.x, b = bh >> 3, h = bh & 7;
  int tid = threadIdx.x;
  const float* kvg = kv + (size_t)bh * 4096;
  for (int i = tid; i < 4096; i += 256) kvs[i] = kvg[i];
  if (tid < 64) kss[tid] = ksum[(size_t)bh * 64 + tid];
  __syncthreads();
  int m = tid & 63;
  for (int s = tid >> 6; s < 257; s += 4) {
    size_t base = ((size_t)(b * 257 + s)) * 512 + h * 64;
    float zp = qf[base + m] * kss[m];
#pragma unroll
    for (int o = 1; o < 64; o <<= 1) zp += __shfl_xor(zp, o);
    float z = 1.0f / (zp + 1e-6f);
    float sum = 0.f;
#pragma unroll
    for (int d = 0; d < 64; ++d) sum += qf[base + d] * kvs[d * 64 + m];
    attn[base + m] = f2b(sum * z);
  }
}

// LayerNorm over D=512 of (xin+add); writes f32 + bf16 shadow.
__global__ __launch_bounds__(256)
void ln_kernel(const float* __restrict__ xin, const float* __restrict__ add,
               const u16* __restrict__ s, const u16* __restrict__ b,
               float* __restrict__ xoutf, u16* __restrict__ xoutb)
{
  __shared__ float red[8];
  int row = blockIdx.x, tid = threadIdx.x;
  size_t base = (size_t)row * 512;
  float v0 = xin[base + tid] + add[base + tid];
  float v1 = xin[base + tid + 256] + add[base + tid + 256];
  float sum = v0 + v1, sq = v0 * v0 + v1 * v1;
#pragma unroll
  for (int o = 1; o < 64; o <<= 1) { sum += __shfl_xor(sum, o); sq += __shfl_xor(sq, o); }
  if ((tid & 63) == 0) { red[tid >> 6] = sum; red[4 + (tid >> 6)] = sq; }
  __syncthreads();
  sum = red[0] + red[1] + red[2] + red[3];
  sq  = red[4] + red[5] + red[6] + red[7];
  float mean = sum * (1.f / 512.f);
  float var  = sq * (1.f / 512.f) - mean * mean;
  float rs = rsqrtf(fmaxf(var, 0.f) + 1e-5f);
  float o0 = (v0 - mean) * rs * b2f(s[tid]) + b2f(b[tid]);
  float o1 = (v1 - mean) * rs * b2f(s[tid + 256]) + b2f(b[tid + 256]);
  xoutf[base + tid] = o0;       xoutf[base + tid + 256] = o1;
  xoutb[base + tid] = f2b(o0);  xoutb[base + tid + 256] = f2b(o1);
}

// final LN on x[b,0,:] + projection to 4 classes; output dtype per flag
__global__ __launch_bounds__(256)
void head_kernel(const float* __restrict__ x, const u16* __restrict__ ls,
                 const u16* __restrict__ lb, const u16* __restrict__ ow,
                 const u16* __restrict__ ob, void* __restrict__ outv,
                 const int* __restrict__ flag)
{
  __shared__ float red[8];
  __shared__ float pr[4][4];
  int b = blockIdx.x, tid = threadIdx.x;
  const float* xr = x + (size_t)b * 257 * 512;
  float v0 = xr[tid], v1 = xr[tid + 256];
  float sum = v0 + v1, sq = v0 * v0 + v1 * v1;
#pragma unroll
  for (int o = 1; o < 64; o <<= 1) { sum += __shfl_xor(sum, o); sq += __shfl_xor(sq, o); }
  if ((tid & 63) == 0) { red[tid >> 6] = sum; red[4 + (tid >> 6)] = sq; }
  __syncthreads();
  sum = red[0] + red[1] + red[2] + red[3];
  sq  = red[4] + red[5] + red[6] + red[7];
  float mean = sum * (1.f / 512.f);
  float var = sq * (1.f / 512.f) - mean * mean;
  float rs = rsqrtf(fmaxf(var, 0.f) + 1e-5f);
  float o0 = (v0 - mean) * rs * b2f(ls[tid]) + b2f(lb[tid]);
  float o1 = (v1 - mean) * rs * b2f(ls[tid + 256]) + b2f(lb[tid + 256]);
  float p[4];
#pragma unroll
  for (int c = 0; c < 4; ++c)
    p[c] = o0 * b2f(ow[tid * 4 + c]) + o1 * b2f(ow[(tid + 256) * 4 + c]);
#pragma unroll
  for (int c = 0; c < 4; ++c)
#pragma unroll
    for (int o = 1; o < 64; o <<= 1) p[c] += __shfl_xor(p[c], o);
  if ((tid & 63) == 0)
#pragma unroll
    for (int c = 0; c < 4; ++c) pr[tid >> 6][c] = p[c];
  __syncthreads();
  if (tid < 4) {
    float s = pr[0][tid] + pr[1][tid] + pr[2][tid] + pr[3][tid] + b2f(ob[tid]);
    if (flag[0]) ((float*)outv)[b * 4 + tid] = s;
    else         ((u16*)outv)[b * 4 + tid] = f2b(s);
  }
}

__global__ __launch_bounds__(256)
void diag_kernel(u16* out, int n, float v)
{
  int i = blockIdx.x * 256 + threadIdx.x;
  if (i < n) out[i] = f2b(v);
}

// ---------------------------------------------------------------------------
extern "C" void kernel_launch(void* const* d_in, const int* in_sizes, int n_in,
                              void* d_out, int out_size, void* d_ws, size_t ws_size,
                              hipStream_t stream)
{
  const int*  inputs = (const int*)d_in[0];
  const void* imask  = d_in[1];
  const void* emb    = d_in[2];
  const void* conv_w = d_in[3];
  const void* conv_b = d_in[4];
  const void* pos    = d_in[5];
  const void* cls    = d_in[6];
  const void* Wq = d_in[7];  const void* bq = d_in[8];
  const void* Wk = d_in[9];  const void* bk = d_in[10];
  const void* Wv = d_in[11]; const void* bv = d_in[12];
  const void* Wo = d_in[13]; const void* bo = d_in[14];
  const void* ln1s = d_in[15]; const void* ln1b = d_in[16];
  const void* ln2s = d_in[17]; const void* ln2b = d_in[18];
  const void* W1 = d_in[19]; const void* b1 = d_in[20];
  const void* W2 = d_in[21]; const void* b2 = d_in[22];
  const void* lnfs = d_in[23]; const void* lnfb = d_in[24];
  const void* outw = d_in[25]; const void* outbb = d_in[26];

  const size_t NEED = 87500000;             // small-path high-water (~87.0 MB)
  if (ws_size < NEED) {
    diag_kernel<<<(out_size + 255) / 256, 256, 0, stream>>>(
        (u16*)d_out, out_size, (float)((double)ws_size / 1048576.0));
    return;
  }
  const bool bigws = ws_size >= 135000000;  // all-layer weight pre-transpose path
  const int  WL    = bigws ? 8 : 1;         // layers of WT storage
  const size_t qs  = bigws ? 786432  : 0;   // per-layer element strides into WT
  const size_t os  = bigws ? 262144  : 0;
  const size_t fs  = bigws ? 1048576 : 0;

  char* p = (char*)d_ws;
  auto take = [&](size_t n) { char* r = p; p += (n + 255) & ~(size_t)255; return r; };
  u16*   WqkvT = (u16*)take(1572864ull * WL);   // (1536,512) bf16 per layer
  u16*   WoT   = (u16*)take(524288ull  * WL);
  u16*   W1T   = (u16*)take(2097152ull * WL);   // (2048,512)
  u16*   W2T   = (u16*)take(2097152ull * WL);   // (512,2048)
  float* xf  = (float*)take(16842752);          // residual f32, persists
  u16*   xb  = (u16*)take(8421376);             // residual bf16 shadow
  // arena: pre-loop = embC (32.77MB); in-loop = qb|kb f32 (attnb over dead kb);
  // FF phase = y1 (exact fit 33,685,504 B)
  char*  arena = take(16842752ull * 2);
  float* qb    = (float*)arena;
  float* kb    = (float*)(arena + 16842752);
  u16*   embC  = (u16*)arena;
  u16*   attnb = (u16*)(arena + 16842752);
  u16*   y1    = (u16*)arena;
  // C block: pre-loop = convT (8.39MB); in-loop = vb bf16 then t0 f32
  char*  Cblk  = take(16842752);
  u16*   convT = (u16*)Cblk;
  u16*   vb    = (u16*)Cblk;
  float* t0    = (float*)Cblk;
  float* kvb   = (float*)take(4194304);
  float* ksumb = (float*)take(65536);
  float* lens  = (float*)take(256);
  int*   flag  = (int*)take(256);
  u16* posC    = (u16*)take(524288);
  u16* conv_bC = (u16*)take(1024);
  u16* clsC    = (u16*)take(1024);
  u16* bqkvC   = (u16*)take(24576);
  u16* boC     = (u16*)take(8192);
  u16* ln1sC   = (u16*)take(8192);
  u16* ln1bC   = (u16*)take(8192);
  u16* ln2sC   = (u16*)take(8192);
  u16* ln2bC   = (u16*)take(8192);
  u16* b1C     = (u16*)take(32768);
  u16* b2C     = (u16*)take(8192);
  u16* lnfsC   = (u16*)take(1024);
  u16* lnfbC   = (u16*)take(1024);
  u16* outwC   = (u16*)take(4096);
  u16* outbC   = (u16*)take(256);

  detect_kernel<<<1, 64, 0, stream>>>(imask, flag);

  PCvt pc = { pos, conv_b, cls, bq, bk, bv, bo,
              ln1s, ln1b, ln2s, ln2b, b1, b2, lnfs, lnfb, outw, outbb,
              posC, conv_bC, clsC, bqkvC, boC,
              ln1sC, ln1bC, ln2sC, ln2bC, b1C, b2C, lnfsC, lnfbC, outwC, outbC,
              flag };
  param_cvt<<<dim3(1024, 12), 256, 0, stream>>>(pc);
  cvt_kernel<<<64000, 256, 0, stream>>>(emb, embC, 16384000, flag);
  conv_repack<<<512, 256, 0, stream>>>(conv_w, convT, flag);
  lengths_kernel<<<32, 256, 0, stream>>>(imask, lens, flag);

  XPose xp = { Wq, Wk, Wv, Wo, W1, W2, WqkvT, WoT, W1T, W2T, 0, flag };
  if (bigws)
    xpose_layer<<<dim3(3072, 8), dim3(32, 8), 0, stream>>>(xp);

  // patch conv: gathered-A GEMM (M=8192, K=8192, N=512) -> x[b,1+n]
  gemm_bt<128, 2, true><<<dim3(64, 4), 256, 0, stream>>>(
      nullptr, convT, 8192, 8192, 512, conv_bC,
      nullptr, nullptr, nullptr, inputs, embC, posC, xf, xb, nullptr);
  cls_kernel<<<32, 256, 0, stream>>>(clsC, posC, xf, xb);

  for (int i = 0; i < 8; ++i) {
    if (!bigws) {
      xp.base = i;
      xpose_layer<<<dim3(3072, 1), dim3(32, 8), 0, stream>>>(xp);
    }
    // fused QKV (N=1536) with in-epilogue rope+elu(+mask): qb/kb f32, vb bf16
    gemm_bt<64, 4, false><<<dim3(129, 12), 256, 0, stream>>>(
        xb, WqkvT + i * qs, 8224, 512, 1536, bqkvC + i * 1536,
        qb, kb, vb, nullptr, nullptr, nullptr, nullptr, nullptr, lens);
    kv_kernel<<<256, 256, 0, stream>>>(kb, vb, kvb, ksumb);       // last read kb, vb
    attn_kernel<<<256, 256, 0, stream>>>(qb, kvb, ksumb, attnb);  // last read qb
    gemm_bt<64, 0, false><<<dim3(129, 4), 256, 0, stream>>>(
        attnb, WoT + i * os, 8224, 512, 512, boC + i * 512,
        t0, nullptr, nullptr, nullptr, nullptr, nullptr, nullptr, nullptr, nullptr);
    ln_kernel<<<8224, 256, 0, stream>>>(xf, t0, ln1sC + i * 512, ln1bC + i * 512, xf, xb);
    gemm_bt<64, 1, false><<<dim3(129, 16), 256, 0, stream>>>(
        xb, W1T + i * fs, 8224, 512, 2048, b1C + i * 2048,
        nullptr, nullptr, y1, nullptr, nullptr, nullptr, nullptr, nullptr, nullptr);
    gemm_bt<64, 0, false><<<dim3(129, 4), 256, 0, stream>>>(
        y1, W2T + i * fs, 8224, 2048, 512, b2C + i * 512,
        t0, nullptr, nullptr, nullptr, nullptr, nullptr, nullptr, nullptr, nullptr);
    ln_kernel<<<8224, 256, 0, stream>>>(xf, t0, ln2sC + i * 512, ln2bC + i * 512, xf, xb);
  }

  head_kernel<<<32, 256, 0, stream>>>(xf, lnfsC, lnfbC, outwC, outbC, d_out, flag);
}